// Round 1
// 963.003 us; speedup vs baseline: 1.0254x; 1.0254x over previous
//
#include <hip/hip_runtime.h>

#define S_IMG 2304
#define S_TXT 512
#define S_ALL 2816
#define DMODEL 3072
#define NH 24
#define HD 128
#define N3 9216

typedef _Float16 half8 __attribute__((ext_vector_type(8)));
typedef _Float16 half4 __attribute__((ext_vector_type(4)));
typedef _Float16 half2v __attribute__((ext_vector_type(2)));
typedef float float4v __attribute__((ext_vector_type(4)));

__device__ __forceinline__ void gld_lds16(const _Float16* g, _Float16* l) {
  __builtin_amdgcn_global_load_lds(
      (const __attribute__((address_space(1))) unsigned int*)g,
      (__attribute__((address_space(3))) unsigned int*)l, 16, 0, 0);
}

__device__ __forceinline__ float4v mfma16(half8 a, half8 b, float4v c) {
  return __builtin_amdgcn_mfma_f32_16x16x32_f16(a, b, c, 0, 0, 0);
}

// ---------------- cast fp32 -> fp16, 8 elems/thread ----------------
__global__ __launch_bounds__(256) void cast_f32_f16(const float* __restrict__ src,
                                                    _Float16* __restrict__ dst, int n8) {
  int i = blockIdx.x * 256 + threadIdx.x;
  if (i >= n8) return;
  float4v a = ((const float4v*)src)[2 * i];
  float4v b = ((const float4v*)src)[2 * i + 1];
  half8 h;
  h[0] = (_Float16)a[0]; h[1] = (_Float16)a[1]; h[2] = (_Float16)a[2]; h[3] = (_Float16)a[3];
  h[4] = (_Float16)b[0]; h[5] = (_Float16)b[1]; h[6] = (_Float16)b[2]; h[7] = (_Float16)b[3];
  ((half8*)dst)[i] = h;
}

// ---------------- pack 6 bias vectors into b3i/b3t ----------------
__global__ __launch_bounds__(256) void bias_pack(const float* __restrict__ bq, const float* __restrict__ bk,
                                                 const float* __restrict__ bv, const float* __restrict__ baq,
                                                 const float* __restrict__ bak, const float* __restrict__ bav,
                                                 float* __restrict__ b3i, float* __restrict__ b3t) {
  int i = blockIdx.x * 256 + threadIdx.x;  // 0..18431
  int j = i % 9216;
  const float* src;
  if (i < 9216) src = (j < 3072) ? bq : (j < 6144) ? bk : bv;
  else          src = (j < 3072) ? baq : (j < 6144) ? bak : bav;
  float v = src[j & 3071];
  if (i < 9216) b3i[j] = v; else b3t[j] = v;
}

// ---------------- C[M][N] = A[M][K] * W[N][K]^T + bias, fp16 in, OT out ------
template <typename OT>
__global__ __launch_bounds__(256) void gemm_f16(const _Float16* __restrict__ A,
                                                const _Float16* __restrict__ W,
                                                const float* __restrict__ bias,
                                                OT* __restrict__ C,
                                                int M, int N, int K) {
  __shared__ __align__(16) _Float16 As[128 * 32];
  __shared__ __align__(16) _Float16 Ws[128 * 32];
  const int tid = threadIdx.x;
  const int wave = tid >> 6, lane = tid & 63;
  const int quad = lane >> 4, col = lane & 15;
  const int wm = (wave >> 1) * 64, wn = (wave & 1) * 64;
  const size_t bm = (size_t)blockIdx.y * 128, bn = (size_t)blockIdx.x * 128;
  const _Float16* Ag = A + (bm + (tid >> 2)) * (size_t)K + (tid & 3) * 8;
  const _Float16* Wg = W + (bn + (tid >> 2)) * (size_t)K + (tid & 3) * 8;

  float4v acc[4][4];
#pragma unroll
  for (int mt = 0; mt < 4; mt++)
#pragma unroll
    for (int nt = 0; nt < 4; nt++) acc[mt][nt] = (float4v){0.f, 0.f, 0.f, 0.f};

  for (int k0 = 0; k0 < K; k0 += 32) {
    gld_lds16(Ag + k0, As + tid * 8);
    gld_lds16(Ag + (size_t)64 * K + k0, As + 2048 + tid * 8);
    gld_lds16(Wg + k0, Ws + tid * 8);
    gld_lds16(Wg + (size_t)64 * K + k0, Ws + 2048 + tid * 8);
    __syncthreads();
    half8 af[4], bf[4];
#pragma unroll
    for (int mt = 0; mt < 4; mt++)
      af[mt] = *(const half8*)&As[(wm + mt * 16 + col) * 32 + quad * 8];
#pragma unroll
    for (int nt = 0; nt < 4; nt++)
      bf[nt] = *(const half8*)&Ws[(wn + nt * 16 + col) * 32 + quad * 8];
#pragma unroll
    for (int mt = 0; mt < 4; mt++)
#pragma unroll
      for (int nt = 0; nt < 4; nt++)
        acc[mt][nt] = mfma16(af[mt], bf[nt], acc[mt][nt]);
    __syncthreads();
  }
#pragma unroll
  for (int mt = 0; mt < 4; mt++)
#pragma unroll
    for (int nt = 0; nt < 4; nt++) {
      const size_t gn = bn + wn + nt * 16 + col;
      const float b = bias[gn];
      const size_t gr = bm + wm + mt * 16 + quad * 4;
#pragma unroll
      for (int i = 0; i < 4; i++)
        C[(gr + i) * (size_t)N + gn] = (OT)(acc[mt][nt][i] + b);
    }
}

// ---------------- RMSNorm + RoPE for Q,K: one wave per (s, h) -------------
// Q additionally scaled by 1/sqrt(HD)*log2(e) so QK^T exits in exp2 domain.
__global__ __launch_bounds__(256) void rmsrope(const _Float16* __restrict__ QKV,  // [S_ALL][9216] fp16
                                               const float* __restrict__ nq, const float* __restrict__ nk,
                                               const float* __restrict__ naq, const float* __restrict__ nak,
                                               const float* __restrict__ icos, const float* __restrict__ isin,
                                               const float* __restrict__ tcos, const float* __restrict__ tsin,
                                               _Float16* __restrict__ Qh,  // [NH][S_ALL][HD]
                                               _Float16* __restrict__ Kh) {
  const float SC = 0.08838834764831845f * 1.4426950408889634f;
  const int wg = blockIdx.x * 4 + (threadIdx.x >> 6);
  const int lane = threadIdx.x & 63;
  const int h = wg % NH;
  const int s = wg / NH;
  const bool is_txt = s < S_TXT;
  const float* nwq = is_txt ? naq : nq;
  const float* nwk = is_txt ? nak : nk;
  const int sr = is_txt ? s : s - S_TXT;
  const float* ct = is_txt ? tcos : icos;
  const float* st = is_txt ? tsin : isin;
  const float cs = ct[sr * 64 + lane];
  const float sn = st[sr * 64 + lane];
  const size_t base = (size_t)s * N3 + h * HD + 2 * lane;
  const half2v q2 = *(const half2v*)&QKV[base];
  const half2v k2 = *(const half2v*)&QKV[base + DMODEL];
  const float qx = (float)q2[0], qy = (float)q2[1];
  const float kx = (float)k2[0], ky = (float)k2[1];
  float sq = qx * qx + qy * qy;
  float sk = kx * kx + ky * ky;
#pragma unroll
  for (int m2 = 32; m2 >= 1; m2 >>= 1) {
    sq += __shfl_xor(sq, m2);
    sk += __shfl_xor(sk, m2);
  }
  const float rq = rsqrtf(sq * (1.f / 128.f) + 1e-6f) * SC;
  const float rk = rsqrtf(sk * (1.f / 128.f) + 1e-6f);
  float wa = nwq[2 * lane], wb = nwq[2 * lane + 1];
  float a = qx * rq * wa, b = qy * rq * wb;
  half2v qo = {(_Float16)(a * cs - b * sn), (_Float16)(a * sn + b * cs)};
  wa = nwk[2 * lane]; wb = nwk[2 * lane + 1];
  a = kx * rk * wa; b = ky * rk * wb;
  half2v ko = {(_Float16)(a * cs - b * sn), (_Float16)(a * sn + b * cs)};
  const size_t ob = ((size_t)h * S_ALL + s) * HD + 2 * lane;
  *(half2v*)&Qh[ob] = qo;
  *(half2v*)&Kh[ob] = ko;
}

// ---------------- V: fp16 [S_ALL][9216] (col offset pre-applied) -> fp16 [NH][HD][S_ALL]
__global__ __launch_bounds__(256) void v_transpose(const _Float16* __restrict__ Vraw,
                                                   _Float16* __restrict__ Vt) {
  __shared__ _Float16 T[64][72];
  const int t = threadIdx.x;
  const int sb = blockIdx.x, db = blockIdx.y, h = blockIdx.z;
  const _Float16* src = Vraw + (size_t)(sb * 64) * N3 + h * HD + db * 64;
#pragma unroll
  for (int it = 0; it < 4; it++) {
    int r = it * 16 + (t >> 4);
    int c = (t & 15) * 4;
    *(half4*)&T[r][c] = *(const half4*)(src + (size_t)r * N3 + c);
  }
  __syncthreads();
  _Float16* dst = Vt + ((size_t)h * HD + db * 64) * S_ALL + sb * 64;
#pragma unroll
  for (int it = 0; it < 4; it++) {
    int r = it * 16 + (t >> 4);  // d
    int c = (t & 15) * 4;        // s
    half4 o;
    o[0] = T[c][r]; o[1] = T[c + 1][r];
    o[2] = T[c + 2][r]; o[3] = T[c + 3][r];
    *(half4*)(dst + (size_t)r * S_ALL + c) = o;
  }
}

// ---------------- flash attention v4 ----------------
// Block = (head, 128 q rows), 4 waves x 32 q-rows (mt=2 tiles of 16).
// K/V fragments reused across both q-tiles -> LDS-read bytes per MFMA halved.
// All LDS tiles slot-XOR-swizzled (T2, both-sides): gld_lds keeps linear dest,
// global source 16B chunk is pre-swizzled chunk^=(row>>1)&3; reads use
// slot = quad ^ ((col>>1)&3). P roundtrip uses the same family, Ps
// double-buffered per mt (no WAR). Max-free softmax unchanged (Q pre-scaled,
// exp2 domain, fixed offset 2 cancels in p/l). LDS 48KB -> 3 blocks/CU.
__global__ __launch_bounds__(256, 3) void attn_kernel(const _Float16* __restrict__ Qh,
                                                      const _Float16* __restrict__ Kh,
                                                      const _Float16* __restrict__ Vt,
                                                      _Float16* __restrict__ O) {  // [S_ALL][DMODEL]
  __shared__ __align__(16) _Float16 Ks[4 * 64 * 32];     // [dslab][64 k][32]  16KB (swz)
  __shared__ __align__(16) _Float16 Vs[2 * 128 * 32];    // [ks2][128 d][32 s] 16KB (swz)
  __shared__ __align__(16) _Float16 Ps[4 * 2 * 2 * 512]; // [wave][mt][ks2][16q][32k] 16KB (swz)
  const int tid = threadIdx.x;
  const int wave = tid >> 6, lane = tid & 63;
  const int quad = lane >> 4, col = lane & 15;
  const int h = blockIdx.y;
  const int q0 = blockIdx.x * 128;
  const _Float16* Qg = Qh + ((size_t)h * S_ALL + q0) * HD;
  const _Float16* Kg = Kh + (size_t)h * S_ALL * HD;
  const _Float16* Vg = Vt + (size_t)h * HD * S_ALL;

  const int fr = (col >> 1) & 3;                    // read-side slot swizzle
  const int srow = tid >> 2;                        // staging row 0..63
  const int schunk = (tid & 3) ^ ((tid >> 3) & 3);  // pre-swizzled source chunk

  // Q fragments straight from global (one-time), 2 q-tiles per wave
  half8 qf[2][4];
#pragma unroll
  for (int mt = 0; mt < 2; mt++)
#pragma unroll
    for (int ks = 0; ks < 4; ks++)
      qf[mt][ks] = *(const half8*)(Qg + (size_t)(wave * 32 + mt * 16 + col) * HD + ks * 32 + quad * 8);

  float l_i[2][4];
  float4v oacc[2][8];
#pragma unroll
  for (int mt = 0; mt < 2; mt++) {
#pragma unroll
    for (int i = 0; i < 4; i++) l_i[mt][i] = 0.f;
#pragma unroll
    for (int nt = 0; nt < 8; nt++) oacc[mt][nt] = (float4v){0.f, 0.f, 0.f, 0.f};
  }

  _Float16* Pw = &Ps[wave * 2048];

  for (int kt = 0; kt < S_ALL / 64; kt++) {
    if (kt > 0) __syncthreads();  // prev iter's Ks/Vs/Ps reads complete
    const int base = kt * 64;
#pragma unroll
    for (int j = 0; j < 4; j++) {
      gld_lds16(Kg + (size_t)(base + srow) * HD + j * 32 + schunk * 8,
                Ks + j * 2048 + tid * 8);
      const int vrow = ((j & 1) * 256 + tid) >> 2;
      gld_lds16(Vg + (size_t)vrow * S_ALL + base + (j >> 1) * 32 + schunk * 8,
                Vs + j * 2048 + tid * 8);
    }
    __syncthreads();

    // S = Q K^T (exp2 domain); per nt: MFMA both q-tiles, then exp2 + P-store
#pragma unroll
    for (int nt = 0; nt < 4; nt++) {
      float4v sf0 = (float4v){0.f, 0.f, 0.f, 0.f};
      float4v sf1 = (float4v){0.f, 0.f, 0.f, 0.f};
#pragma unroll
      for (int ks = 0; ks < 4; ks++) {
        half8 kf = *(const half8*)&Ks[ks * 2048 + (nt * 16 + col) * 32 + (quad ^ fr) * 8];
        sf0 = mfma16(qf[0][ks], kf, sf0);
        sf1 = mfma16(qf[1][ks], kf, sf1);
      }
#pragma unroll
      for (int mt = 0; mt < 2; mt++) {
        _Float16* Pt = Pw + mt * 1024 + (nt >> 1) * 512;
#pragma unroll
        for (int i = 0; i < 4; i++) {
          const float s = (mt == 0) ? sf0[i] : sf1[i];
          const float p = exp2f(s - 2.0f);
          l_i[mt][i] += p;
          const int q = quad * 4 + i;
          const int slot = ((nt & 1) * 2 + (col >> 3)) ^ ((q >> 1) & 3);
          Pt[q * 32 + slot * 8 + (col & 7)] = (_Float16)p;
        }
      }
    }
    asm volatile("s_waitcnt lgkmcnt(0)" ::: "memory");
    __builtin_amdgcn_sched_barrier(0);
    // O += P V (vf reused across both q-tiles)
#pragma unroll
    for (int ks = 0; ks < 2; ks++) {
      half8 pf0 = *(const half8*)&Pw[ks * 512 + col * 32 + (quad ^ fr) * 8];
      half8 pf1 = *(const half8*)&Pw[1024 + ks * 512 + col * 32 + (quad ^ fr) * 8];
#pragma unroll
      for (int nt = 0; nt < 8; nt++) {
        half8 vf = *(const half8*)&Vs[ks * 4096 + (nt * 16 + col) * 32 + (quad ^ fr) * 8];
        oacc[0][nt] = mfma16(pf0, vf, oacc[0][nt]);
        oacc[1][nt] = mfma16(pf1, vf, oacc[1][nt]);
      }
    }
  }
  // final l reduction across the 16 lanes sharing a quad (row = quad*4+i)
#pragma unroll
  for (int mt = 0; mt < 2; mt++)
#pragma unroll
    for (int i = 0; i < 4; i++) {
      float l = l_i[mt][i];
      l += __shfl_xor(l, 1);
      l += __shfl_xor(l, 2);
      l += __shfl_xor(l, 4);
      l += __shfl_xor(l, 8);
      l_i[mt][i] = 1.0f / l;
    }
#pragma unroll
  for (int mt = 0; mt < 2; mt++)
#pragma unroll
    for (int nt = 0; nt < 8; nt++)
#pragma unroll
      for (int i = 0; i < 4; i++) {
        const int s = q0 + wave * 32 + mt * 16 + quad * 4 + i;
        O[(size_t)s * DMODEL + h * HD + nt * 16 + col] = (_Float16)(oacc[mt][nt][i] * l_i[mt][i]);
      }
}

extern "C" void kernel_launch(void* const* d_in, const int* in_sizes, int n_in,
                              void* d_out, int out_size, void* d_ws, size_t ws_size,
                              hipStream_t stream) {
  const float* hs   = (const float*)d_in[0];
  const float* ehs  = (const float*)d_in[1];
  const float* wq   = (const float*)d_in[2];
  const float* bq   = (const float*)d_in[3];
  const float* wk   = (const float*)d_in[4];
  const float* bk   = (const float*)d_in[5];
  const float* wv   = (const float*)d_in[6];
  const float* bv   = (const float*)d_in[7];
  const float* waq  = (const float*)d_in[8];
  const float* baq  = (const float*)d_in[9];
  const float* wak  = (const float*)d_in[10];
  const float* bak  = (const float*)d_in[11];
  const float* wav  = (const float*)d_in[12];
  const float* bav  = (const float*)d_in[13];
  const float* nq   = (const float*)d_in[14];
  const float* nk   = (const float*)d_in[15];
  const float* naq  = (const float*)d_in[16];
  const float* nak  = (const float*)d_in[17];
  const float* wo   = (const float*)d_in[18];
  const float* bo   = (const float*)d_in[19];
  const float* wao  = (const float*)d_in[20];
  const float* bao  = (const float*)d_in[21];
  const float* icos = (const float*)d_in[22];
  const float* isin = (const float*)d_in[23];
  const float* tcos = (const float*)d_in[24];
  const float* tsin = (const float*)d_in[25];

  // ---- workspace layout (143.2 MB total, buffers reused via stream order) ----
  char* w = (char*)d_ws;
  _Float16* wbuf = (_Float16*)(w + 0);          // 56.6 MB: w3 casts; later qh/kh
  _Float16* qh   = wbuf;                         // [24][2816][128] fp16
  _Float16* kh   = (_Float16*)(w + 17301504);
  _Float16* xi   = (_Float16*)(w + 56623104);    // 2304x3072 fp16
  _Float16* xt   = (_Float16*)(w + 70778880);    // 512x3072 fp16
  _Float16* ob   = (_Float16*)(w + 56623104);    // [2816][3072] fp16 (aliases xi/xt)
  float*    b3i  = (float*)(w + 73924608);
  float*    b3t  = (float*)(w + 73961472);
  _Float16* qkv  = (_Float16*)(w + 73998336);    // [2816][9216] fp16 (txt rows 0..511)
  _Float16* vt   = (_Float16*)(w + 125902848);   // [24][128][2816] fp16
  float* out = (float*)d_out;

  const size_t WSZ = (size_t)DMODEL * DMODEL;   // 9437184

  cast_f32_f16<<<3456, 256, 0, stream>>>(hs, xi, 884736);
  cast_f32_f16<<<768, 256, 0, stream>>>(ehs, xt, 196608);
  bias_pack<<<72, 256, 0, stream>>>(bq, bk, bv, baq, bak, bav, b3i, b3t);

  // img QKV
  cast_f32_f16<<<4608, 256, 0, stream>>>(wq, wbuf, WSZ / 8);
  cast_f32_f16<<<4608, 256, 0, stream>>>(wk, wbuf + WSZ, WSZ / 8);
  cast_f32_f16<<<4608, 256, 0, stream>>>(wv, wbuf + 2 * WSZ, WSZ / 8);
  gemm_f16<_Float16><<<dim3(72, 18), 256, 0, stream>>>(xi, wbuf, b3i, qkv + (size_t)512 * N3, 2304, N3, DMODEL);
  // txt QKV
  cast_f32_f16<<<4608, 256, 0, stream>>>(waq, wbuf, WSZ / 8);
  cast_f32_f16<<<4608, 256, 0, stream>>>(wak, wbuf + WSZ, WSZ / 8);
  cast_f32_f16<<<4608, 256, 0, stream>>>(wav, wbuf + 2 * WSZ, WSZ / 8);
  gemm_f16<_Float16><<<dim3(72, 4), 256, 0, stream>>>(xt, wbuf, b3t, qkv, 512, N3, DMODEL);

  rmsrope<<<16896, 256, 0, stream>>>(qkv, nq, nk, naq, nak, icos, isin, tcos, tsin, qh, kh);
  v_transpose<<<dim3(44, 2, 24), 256, 0, stream>>>(qkv + 2 * DMODEL, vt);
  attn_kernel<<<dim3(22, 24), 256, 0, stream>>>(qh, kh, vt, ob);

  _Float16* wo16 = (_Float16*)(w + 73998336);   // reuse qkv region (dead after attn)
  cast_f32_f16<<<4608, 256, 0, stream>>>(wo, wo16, WSZ / 8);
  gemm_f16<float><<<dim3(24, 18), 256, 0, stream>>>(ob + (size_t)512 * DMODEL, wo16, bo, out, 2304, DMODEL, DMODEL);
  cast_f32_f16<<<4608, 256, 0, stream>>>(wao, wo16, WSZ / 8);
  gemm_f16<float><<<dim3(24, 4), 256, 0, stream>>>(ob, wo16, bao, out + (size_t)2304 * DMODEL, 512, DMODEL, DMODEL);
}

// Round 2
// 946.506 us; speedup vs baseline: 1.0432x; 1.0174x over previous
//
#include <hip/hip_runtime.h>

#define S_IMG 2304
#define S_TXT 512
#define S_ALL 2816
#define DMODEL 3072
#define NH 24
#define HD 128
#define N3 9216

typedef _Float16 half8 __attribute__((ext_vector_type(8)));
typedef _Float16 half4 __attribute__((ext_vector_type(4)));
typedef _Float16 half2v __attribute__((ext_vector_type(2)));
typedef float float4v __attribute__((ext_vector_type(4)));

__device__ __forceinline__ void gld_lds16(const _Float16* g, _Float16* l) {
  __builtin_amdgcn_global_load_lds(
      (const __attribute__((address_space(1))) unsigned int*)g,
      (__attribute__((address_space(3))) unsigned int*)l, 16, 0, 0);
}

__device__ __forceinline__ float4v mfma16(half8 a, half8 b, float4v c) {
  return __builtin_amdgcn_mfma_f32_16x16x32_f16(a, b, c, 0, 0, 0);
}

// bijective XCD-aware block remap (m204 formula)
__device__ __forceinline__ int xcd_swz(int bid, int nwg) {
  const int q = nwg >> 3, r = nwg & 7;
  const int x = bid & 7, l = bid >> 3;
  return (x < r ? x * (q + 1) : r * (q + 1) + (x - r) * q) + l;
}

// ---------------- cast fp32 -> fp16, 8 elems/thread ----------------
__global__ __launch_bounds__(256) void cast_f32_f16(const float* __restrict__ src,
                                                    _Float16* __restrict__ dst, int n8) {
  int i = blockIdx.x * 256 + threadIdx.x;
  if (i >= n8) return;
  float4v a = ((const float4v*)src)[2 * i];
  float4v b = ((const float4v*)src)[2 * i + 1];
  half8 h;
  h[0] = (_Float16)a[0]; h[1] = (_Float16)a[1]; h[2] = (_Float16)a[2]; h[3] = (_Float16)a[3];
  h[4] = (_Float16)b[0]; h[5] = (_Float16)b[1]; h[6] = (_Float16)b[2]; h[7] = (_Float16)b[3];
  ((half8*)dst)[i] = h;
}

// ---------------- pack 6 bias vectors into b3i/b3t ----------------
__global__ __launch_bounds__(256) void bias_pack(const float* __restrict__ bq, const float* __restrict__ bk,
                                                 const float* __restrict__ bv, const float* __restrict__ baq,
                                                 const float* __restrict__ bak, const float* __restrict__ bav,
                                                 float* __restrict__ b3i, float* __restrict__ b3t) {
  int i = blockIdx.x * 256 + threadIdx.x;  // 0..18431
  int j = i % 9216;
  const float* src;
  if (i < 9216) src = (j < 3072) ? bq : (j < 6144) ? bk : bv;
  else          src = (j < 3072) ? baq : (j < 6144) ? bak : bav;
  float v = src[j & 3071];
  if (i < 9216) b3i[j] = v; else b3t[j] = v;
}

// ---------------- 2-phase 128^2 GEMM (kept for txt QKV: M=512) ----------------
template <typename OT>
__global__ __launch_bounds__(256) void gemm_f16(const _Float16* __restrict__ A,
                                                const _Float16* __restrict__ W,
                                                const float* __restrict__ bias,
                                                OT* __restrict__ C,
                                                int M, int N, int K) {
  __shared__ __align__(16) _Float16 As[128 * 32];
  __shared__ __align__(16) _Float16 Ws[128 * 32];
  const int tid = threadIdx.x;
  const int wave = tid >> 6, lane = tid & 63;
  const int quad = lane >> 4, col = lane & 15;
  const int wm = (wave >> 1) * 64, wn = (wave & 1) * 64;
  const size_t bm = (size_t)blockIdx.y * 128, bn = (size_t)blockIdx.x * 128;
  const _Float16* Ag = A + (bm + (tid >> 2)) * (size_t)K + (tid & 3) * 8;
  const _Float16* Wg = W + (bn + (tid >> 2)) * (size_t)K + (tid & 3) * 8;

  float4v acc[4][4];
#pragma unroll
  for (int mt = 0; mt < 4; mt++)
#pragma unroll
    for (int nt = 0; nt < 4; nt++) acc[mt][nt] = (float4v){0.f, 0.f, 0.f, 0.f};

  for (int k0 = 0; k0 < K; k0 += 32) {
    gld_lds16(Ag + k0, As + tid * 8);
    gld_lds16(Ag + (size_t)64 * K + k0, As + 2048 + tid * 8);
    gld_lds16(Wg + k0, Ws + tid * 8);
    gld_lds16(Wg + (size_t)64 * K + k0, Ws + 2048 + tid * 8);
    __syncthreads();
    half8 af[4], bf[4];
#pragma unroll
    for (int mt = 0; mt < 4; mt++)
      af[mt] = *(const half8*)&As[(wm + mt * 16 + col) * 32 + quad * 8];
#pragma unroll
    for (int nt = 0; nt < 4; nt++)
      bf[nt] = *(const half8*)&Ws[(wn + nt * 16 + col) * 32 + quad * 8];
#pragma unroll
    for (int mt = 0; mt < 4; mt++)
#pragma unroll
      for (int nt = 0; nt < 4; nt++)
        acc[mt][nt] = mfma16(af[mt], bf[nt], acc[mt][nt]);
    __syncthreads();
  }
#pragma unroll
  for (int mt = 0; mt < 4; mt++)
#pragma unroll
    for (int nt = 0; nt < 4; nt++) {
      const size_t gn = bn + wn + nt * 16 + col;
      const float b = bias[gn];
      const size_t gr = bm + wm + mt * 16 + quad * 4;
#pragma unroll
      for (int i = 0; i < 4; i++)
        C[(gr + i) * (size_t)N + gn] = (OT)(acc[mt][nt][i] + b);
    }
}

// ---------------- 256^2 BK=64 deep-pipelined GEMM core ----------------
// 8 waves (2M x 4N), double-buffered 128KB LDS, counted vmcnt(8) (tile kt+1's
// loads stay in flight across the whole K-iteration; no mid-loop drain),
// chunk-XOR swizzle (source-side pre-swizzle + swizzled ds_read, <=2-way banks),
// setprio(1) around each 16-MFMA quadrant cluster.
// Safety: gld_lds into buffer b is only issued after the barrier that postdates
// all reads of b (reads of tile kt complete before boundary kt+1; tile kt+2
// into the same buffer is issued at boundary kt+1).
template <typename OT>
__device__ __forceinline__ void gemm256_core(const _Float16* __restrict__ A0,  // at (bm, 0), row stride K
                                             const _Float16* __restrict__ W0,  // at (bn, 0), row stride K
                                             const float* __restrict__ bias0,  // at bn
                                             OT* __restrict__ C0,              // at (bm, bn), row stride ldc
                                             int K, int ldc) {
  __shared__ __align__(16) _Float16 Asm[2][16384];  // [buf][256 rows][64 k] 64KB
  __shared__ __align__(16) _Float16 Wsm[2][16384];  // [buf][256 rows][64 k] 64KB
  const int tid = threadIdx.x;                // 0..511
  const int wave = tid >> 6, lane = tid & 63;
  const int quad = lane >> 4, col = lane & 15;
  const int wm = (wave >> 2) * 128;           // 2 M-waves
  const int wn = (wave & 3) * 64;             // 4 N-waves
  // staging: thread t covers LDS row r*64+(t>>3), chunk t&7 (linear dest);
  // source chunk pre-swizzled by row&7 so LDS[row][c] holds global chunk c^(row&7)
  const int srow = tid >> 3;
  const int dst = tid * 8;
  const _Float16* Asrc = A0 + (size_t)srow * K + (((tid & 7) ^ (srow & 7)) * 8);
  const _Float16* Wsrc = W0 + (size_t)srow * K + (((tid & 7) ^ (srow & 7)) * 8);

  auto stage = [&](int b, int k0) {
#pragma unroll
    for (int r = 0; r < 4; r++) {
      gld_lds16(Asrc + (size_t)(r * 64) * K + k0, &Asm[b][r * 4096 + dst]);
      gld_lds16(Wsrc + (size_t)(r * 64) * K + k0, &Wsm[b][r * 4096 + dst]);
    }
  };

  float4v acc[8][4];
#pragma unroll
  for (int mr = 0; mr < 8; mr++)
#pragma unroll
    for (int nr = 0; nr < 4; nr++) acc[mr][nr] = (float4v){0.f, 0.f, 0.f, 0.f};

  const int NT = K >> 6;
  stage(0, 0);

  for (int kt = 0; kt < NT; kt++) {
    const int c = kt & 1;
    asm volatile("" ::: "memory");
    __builtin_amdgcn_s_barrier();   // all waves done reading buf c^1 (iter kt-1)
    asm volatile("" ::: "memory");
    if (kt + 1 < NT) {
      stage(c ^ 1, (kt + 1) << 6);  // prefetch next tile; consumed next iter
      asm volatile("s_waitcnt vmcnt(8)" ::: "memory");  // tile kt landed; kt+1 in flight
    } else {
      asm volatile("s_waitcnt vmcnt(0)" ::: "memory");
    }
    asm volatile("" ::: "memory");
    __builtin_amdgcn_s_barrier();   // all waves' shares of tile kt landed
    asm volatile("" ::: "memory");
    const _Float16* Ab = Asm[c];
    const _Float16* Wb = Wsm[c];
#pragma unroll
    for (int ph = 0; ph < 4; ph++) {
      const int mh = ph >> 1, nh = ph & 1;
      half8 af[4][2], bf[2][2];
#pragma unroll
      for (int i = 0; i < 4; i++)
#pragma unroll
        for (int kk = 0; kk < 2; kk++)
          af[i][kk] = *(const half8*)&Ab[(wm + mh * 64 + i * 16 + col) * 64 +
                                         (((kk << 2) | quad) ^ (col & 7)) * 8];
#pragma unroll
      for (int j = 0; j < 2; j++)
#pragma unroll
        for (int kk = 0; kk < 2; kk++)
          bf[j][kk] = *(const half8*)&Wb[(wn + nh * 32 + j * 16 + col) * 64 +
                                         (((kk << 2) | quad) ^ (col & 7)) * 8];
      __builtin_amdgcn_s_setprio(1);
#pragma unroll
      for (int kk = 0; kk < 2; kk++)
#pragma unroll
        for (int i = 0; i < 4; i++)
#pragma unroll
          for (int j = 0; j < 2; j++)
            acc[mh * 4 + i][nh * 2 + j] = mfma16(af[i][kk], bf[j][kk], acc[mh * 4 + i][nh * 2 + j]);
      __builtin_amdgcn_s_setprio(0);
    }
  }
  // epilogue
#pragma unroll
  for (int nr = 0; nr < 4; nr++) {
    const int gn = wn + nr * 16 + col;
    const float bv = bias0[gn];
#pragma unroll
    for (int mr = 0; mr < 8; mr++) {
      const int gr = wm + mr * 16 + quad * 4;
#pragma unroll
      for (int ii = 0; ii < 4; ii++)
        C0[(size_t)(gr + ii) * ldc + gn] = (OT)(acc[mr][nr][ii] + bv);
    }
  }
}

// img QKV: M=2304 (9 tiles), N=9216 (36 tiles), K=3072. C already offset to row 512.
__global__ __launch_bounds__(512, 2) void gemm256_qkv(const _Float16* __restrict__ A,
                                                      const _Float16* __restrict__ W,
                                                      const float* __restrict__ bias,
                                                      _Float16* __restrict__ C) {
  const int wgid = xcd_swz(blockIdx.x, 36 * 9);
  const int bx = wgid / 9, by = wgid % 9;  // W-panel-major within an XCD chunk
  gemm256_core<_Float16>(A + (size_t)by * 256 * 3072,
                         W + (size_t)bx * 256 * 3072,
                         bias + bx * 256,
                         C + (size_t)by * 256 * 9216 + bx * 256,
                         3072, 9216);
}

// merged out-proj: img (9 M-tiles, W=wo) + txt (2 M-tiles, W=wao); N=3072 (12 tiles)
__global__ __launch_bounds__(512, 2) void gemm256_out(const _Float16* __restrict__ ob,
                                                      const _Float16* __restrict__ wo16,
                                                      const float* __restrict__ bo,
                                                      const _Float16* __restrict__ wao16,
                                                      const float* __restrict__ bao,
                                                      float* __restrict__ out) {
  const int wgid = xcd_swz(blockIdx.x, 12 * 11);
  const int bx = wgid / 11, by = wgid % 11;
  const _Float16* A;
  const _Float16* W;
  const float* bias;
  float* C;
  if (by < 9) {  // img rows 512.. of ob -> out rows 0..2303
    A = ob + ((size_t)512 + (size_t)by * 256) * 3072;
    W = wo16; bias = bo;
    C = out + (size_t)by * 256 * 3072;
  } else {       // txt rows 0..511 of ob -> second output
    A = ob + (size_t)(by - 9) * 256 * 3072;
    W = wao16; bias = bao;
    C = out + (size_t)2304 * 3072 + (size_t)(by - 9) * 256 * 3072;
  }
  gemm256_core<float>(A, W + (size_t)bx * 256 * 3072, bias + bx * 256, C + bx * 256,
                      3072, 3072);
}

// ---------------- RMSNorm + RoPE for Q,K: one wave per (s, h) -------------
__global__ __launch_bounds__(256) void rmsrope(const _Float16* __restrict__ QKV,  // [S_ALL][9216] fp16
                                               const float* __restrict__ nq, const float* __restrict__ nk,
                                               const float* __restrict__ naq, const float* __restrict__ nak,
                                               const float* __restrict__ icos, const float* __restrict__ isin,
                                               const float* __restrict__ tcos, const float* __restrict__ tsin,
                                               _Float16* __restrict__ Qh,  // [NH][S_ALL][HD]
                                               _Float16* __restrict__ Kh) {
  const float SC = 0.08838834764831845f * 1.4426950408889634f;
  const int wg = blockIdx.x * 4 + (threadIdx.x >> 6);
  const int lane = threadIdx.x & 63;
  const int h = wg % NH;
  const int s = wg / NH;
  const bool is_txt = s < S_TXT;
  const float* nwq = is_txt ? naq : nq;
  const float* nwk = is_txt ? nak : nk;
  const int sr = is_txt ? s : s - S_TXT;
  const float* ct = is_txt ? tcos : icos;
  const float* st = is_txt ? tsin : isin;
  const float cs = ct[sr * 64 + lane];
  const float sn = st[sr * 64 + lane];
  const size_t base = (size_t)s * N3 + h * HD + 2 * lane;
  const half2v q2 = *(const half2v*)&QKV[base];
  const half2v k2 = *(const half2v*)&QKV[base + DMODEL];
  const float qx = (float)q2[0], qy = (float)q2[1];
  const float kx = (float)k2[0], ky = (float)k2[1];
  float sq = qx * qx + qy * qy;
  float sk = kx * kx + ky * ky;
#pragma unroll
  for (int m2 = 32; m2 >= 1; m2 >>= 1) {
    sq += __shfl_xor(sq, m2);
    sk += __shfl_xor(sk, m2);
  }
  const float rq = rsqrtf(sq * (1.f / 128.f) + 1e-6f) * SC;
  const float rk = rsqrtf(sk * (1.f / 128.f) + 1e-6f);
  float wa = nwq[2 * lane], wb = nwq[2 * lane + 1];
  float a = qx * rq * wa, b = qy * rq * wb;
  half2v qo = {(_Float16)(a * cs - b * sn), (_Float16)(a * sn + b * cs)};
  wa = nwk[2 * lane]; wb = nwk[2 * lane + 1];
  a = kx * rk * wa; b = ky * rk * wb;
  half2v ko = {(_Float16)(a * cs - b * sn), (_Float16)(a * sn + b * cs)};
  const size_t ob = ((size_t)h * S_ALL + s) * HD + 2 * lane;
  *(half2v*)&Qh[ob] = qo;
  *(half2v*)&Kh[ob] = ko;
}

// ---------------- V: fp16 [S_ALL][9216] (col offset pre-applied) -> fp16 [NH][HD][S_ALL]
__global__ __launch_bounds__(256) void v_transpose(const _Float16* __restrict__ Vraw,
                                                   _Float16* __restrict__ Vt) {
  __shared__ _Float16 T[64][72];
  const int t = threadIdx.x;
  const int sb = blockIdx.x, db = blockIdx.y, h = blockIdx.z;
  const _Float16* src = Vraw + (size_t)(sb * 64) * N3 + h * HD + db * 64;
#pragma unroll
  for (int it = 0; it < 4; it++) {
    int r = it * 16 + (t >> 4);
    int c = (t & 15) * 4;
    *(half4*)&T[r][c] = *(const half4*)(src + (size_t)r * N3 + c);
  }
  __syncthreads();
  _Float16* dst = Vt + ((size_t)h * HD + db * 64) * S_ALL + sb * 64;
#pragma unroll
  for (int it = 0; it < 4; it++) {
    int r = it * 16 + (t >> 4);  // d
    int c = (t & 15) * 4;        // s
    half4 o;
    o[0] = T[c][r]; o[1] = T[c + 1][r];
    o[2] = T[c + 2][r]; o[3] = T[c + 3][r];
    *(half4*)(dst + (size_t)r * S_ALL + c) = o;
  }
}

// ---------------- flash attention v4 (unchanged from round 1) ----------------
__global__ __launch_bounds__(256, 3) void attn_kernel(const _Float16* __restrict__ Qh,
                                                      const _Float16* __restrict__ Kh,
                                                      const _Float16* __restrict__ Vt,
                                                      _Float16* __restrict__ O) {  // [S_ALL][DMODEL]
  __shared__ __align__(16) _Float16 Ks[4 * 64 * 32];     // [dslab][64 k][32]  16KB (swz)
  __shared__ __align__(16) _Float16 Vs[2 * 128 * 32];    // [ks2][128 d][32 s] 16KB (swz)
  __shared__ __align__(16) _Float16 Ps[4 * 2 * 2 * 512]; // [wave][mt][ks2][16q][32k] 16KB (swz)
  const int tid = threadIdx.x;
  const int wave = tid >> 6, lane = tid & 63;
  const int quad = lane >> 4, col = lane & 15;
  const int h = blockIdx.y;
  const int q0 = blockIdx.x * 128;
  const _Float16* Qg = Qh + ((size_t)h * S_ALL + q0) * HD;
  const _Float16* Kg = Kh + (size_t)h * S_ALL * HD;
  const _Float16* Vg = Vt + (size_t)h * HD * S_ALL;

  const int fr = (col >> 1) & 3;                    // read-side slot swizzle
  const int srow = tid >> 2;                        // staging row 0..63
  const int schunk = (tid & 3) ^ ((tid >> 3) & 3);  // pre-swizzled source chunk

  half8 qf[2][4];
#pragma unroll
  for (int mt = 0; mt < 2; mt++)
#pragma unroll
    for (int ks = 0; ks < 4; ks++)
      qf[mt][ks] = *(const half8*)(Qg + (size_t)(wave * 32 + mt * 16 + col) * HD + ks * 32 + quad * 8);

  float l_i[2][4];
  float4v oacc[2][8];
#pragma unroll
  for (int mt = 0; mt < 2; mt++) {
#pragma unroll
    for (int i = 0; i < 4; i++) l_i[mt][i] = 0.f;
#pragma unroll
    for (int nt = 0; nt < 8; nt++) oacc[mt][nt] = (float4v){0.f, 0.f, 0.f, 0.f};
  }

  _Float16* Pw = &Ps[wave * 2048];

  for (int kt = 0; kt < S_ALL / 64; kt++) {
    if (kt > 0) __syncthreads();
    const int base = kt * 64;
#pragma unroll
    for (int j = 0; j < 4; j++) {
      gld_lds16(Kg + (size_t)(base + srow) * HD + j * 32 + schunk * 8,
                Ks + j * 2048 + tid * 8);
      const int vrow = ((j & 1) * 256 + tid) >> 2;
      gld_lds16(Vg + (size_t)vrow * S_ALL + base + (j >> 1) * 32 + schunk * 8,
                Vs + j * 2048 + tid * 8);
    }
    __syncthreads();

#pragma unroll
    for (int nt = 0; nt < 4; nt++) {
      float4v sf0 = (float4v){0.f, 0.f, 0.f, 0.f};
      float4v sf1 = (float4v){0.f, 0.f, 0.f, 0.f};
#pragma unroll
      for (int ks = 0; ks < 4; ks++) {
        half8 kf = *(const half8*)&Ks[ks * 2048 + (nt * 16 + col) * 32 + (quad ^ fr) * 8];
        sf0 = mfma16(qf[0][ks], kf, sf0);
        sf1 = mfma16(qf[1][ks], kf, sf1);
      }
#pragma unroll
      for (int mt = 0; mt < 2; mt++) {
        _Float16* Pt = Pw + mt * 1024 + (nt >> 1) * 512;
#pragma unroll
        for (int i = 0; i < 4; i++) {
          const float s = (mt == 0) ? sf0[i] : sf1[i];
          const float p = exp2f(s - 2.0f);
          l_i[mt][i] += p;
          const int q = quad * 4 + i;
          const int slot = ((nt & 1) * 2 + (col >> 3)) ^ ((q >> 1) & 3);
          Pt[q * 32 + slot * 8 + (col & 7)] = (_Float16)p;
        }
      }
    }
    asm volatile("s_waitcnt lgkmcnt(0)" ::: "memory");
    __builtin_amdgcn_sched_barrier(0);
#pragma unroll
    for (int ks = 0; ks < 2; ks++) {
      half8 pf0 = *(const half8*)&Pw[ks * 512 + col * 32 + (quad ^ fr) * 8];
      half8 pf1 = *(const half8*)&Pw[1024 + ks * 512 + col * 32 + (quad ^ fr) * 8];
#pragma unroll
      for (int nt = 0; nt < 8; nt++) {
        half8 vf = *(const half8*)&Vs[ks * 4096 + (nt * 16 + col) * 32 + (quad ^ fr) * 8];
        oacc[0][nt] = mfma16(pf0, vf, oacc[0][nt]);
        oacc[1][nt] = mfma16(pf1, vf, oacc[1][nt]);
      }
    }
  }
#pragma unroll
  for (int mt = 0; mt < 2; mt++)
#pragma unroll
    for (int i = 0; i < 4; i++) {
      float l = l_i[mt][i];
      l += __shfl_xor(l, 1);
      l += __shfl_xor(l, 2);
      l += __shfl_xor(l, 4);
      l += __shfl_xor(l, 8);
      l_i[mt][i] = 1.0f / l;
    }
#pragma unroll
  for (int mt = 0; mt < 2; mt++)
#pragma unroll
    for (int nt = 0; nt < 8; nt++)
#pragma unroll
      for (int i = 0; i < 4; i++) {
        const int s = q0 + wave * 32 + mt * 16 + quad * 4 + i;
        O[(size_t)s * DMODEL + h * HD + nt * 16 + col] = (_Float16)(oacc[mt][nt][i] * l_i[mt][i]);
      }
}

extern "C" void kernel_launch(void* const* d_in, const int* in_sizes, int n_in,
                              void* d_out, int out_size, void* d_ws, size_t ws_size,
                              hipStream_t stream) {
  const float* hs   = (const float*)d_in[0];
  const float* ehs  = (const float*)d_in[1];
  const float* wq   = (const float*)d_in[2];
  const float* bq   = (const float*)d_in[3];
  const float* wk   = (const float*)d_in[4];
  const float* bk   = (const float*)d_in[5];
  const float* wv   = (const float*)d_in[6];
  const float* bv   = (const float*)d_in[7];
  const float* waq  = (const float*)d_in[8];
  const float* baq  = (const float*)d_in[9];
  const float* wak  = (const float*)d_in[10];
  const float* bak  = (const float*)d_in[11];
  const float* wav  = (const float*)d_in[12];
  const float* bav  = (const float*)d_in[13];
  const float* nq   = (const float*)d_in[14];
  const float* nk   = (const float*)d_in[15];
  const float* naq  = (const float*)d_in[16];
  const float* nak  = (const float*)d_in[17];
  const float* wo   = (const float*)d_in[18];
  const float* bo   = (const float*)d_in[19];
  const float* wao  = (const float*)d_in[20];
  const float* bao  = (const float*)d_in[21];
  const float* icos = (const float*)d_in[22];
  const float* isin = (const float*)d_in[23];
  const float* tcos = (const float*)d_in[24];
  const float* tsin = (const float*)d_in[25];

  // ---- workspace layout (143.2 MB total, buffers reused via stream order) ----
  char* w = (char*)d_ws;
  _Float16* wbuf = (_Float16*)(w + 0);          // 56.6 MB: w3 casts; later qh/kh
  _Float16* qh   = wbuf;                         // [24][2816][128] fp16
  _Float16* kh   = (_Float16*)(w + 17301504);
  _Float16* xi   = (_Float16*)(w + 56623104);    // 2304x3072 fp16
  _Float16* xt   = (_Float16*)(w + 70778880);    // 512x3072 fp16
  _Float16* ob   = (_Float16*)(w + 56623104);    // [2816][3072] fp16 (aliases xi/xt)
  float*    b3i  = (float*)(w + 73924608);
  float*    b3t  = (float*)(w + 73961472);
  _Float16* qkv  = (_Float16*)(w + 73998336);    // [2816][9216] fp16 (txt rows 0..511)
  _Float16* vt   = (_Float16*)(w + 125902848);   // [24][128][2816] fp16
  float* out = (float*)d_out;

  const size_t WSZ = (size_t)DMODEL * DMODEL;   // 9437184

  cast_f32_f16<<<3456, 256, 0, stream>>>(hs, xi, 884736);
  cast_f32_f16<<<768, 256, 0, stream>>>(ehs, xt, 196608);
  bias_pack<<<72, 256, 0, stream>>>(bq, bk, bv, baq, bak, bav, b3i, b3t);

  // img QKV (256^2 pipelined)
  cast_f32_f16<<<4608, 256, 0, stream>>>(wq, wbuf, WSZ / 8);
  cast_f32_f16<<<4608, 256, 0, stream>>>(wk, wbuf + WSZ, WSZ / 8);
  cast_f32_f16<<<4608, 256, 0, stream>>>(wv, wbuf + 2 * WSZ, WSZ / 8);
  gemm256_qkv<<<324, 512, 0, stream>>>(xi, wbuf, b3i, qkv + (size_t)512 * N3);
  // txt QKV (128^2, M=512)
  cast_f32_f16<<<4608, 256, 0, stream>>>(waq, wbuf, WSZ / 8);
  cast_f32_f16<<<4608, 256, 0, stream>>>(wak, wbuf + WSZ, WSZ / 8);
  cast_f32_f16<<<4608, 256, 0, stream>>>(wav, wbuf + 2 * WSZ, WSZ / 8);
  gemm_f16<_Float16><<<dim3(72, 4), 256, 0, stream>>>(xt, wbuf, b3t, qkv, 512, N3, DMODEL);

  rmsrope<<<16896, 256, 0, stream>>>(qkv, nq, nk, naq, nak, icos, isin, tcos, tsin, qh, kh);
  v_transpose<<<dim3(44, 2, 24), 256, 0, stream>>>(qkv + 2 * DMODEL, vt);
  attn_kernel<<<dim3(22, 24), 256, 0, stream>>>(qh, kh, vt, ob);

  // merged out-proj: both weights cast into the dead qkv region
  _Float16* wo16  = (_Float16*)(w + 73998336);
  _Float16* wao16 = wo16 + WSZ;
  cast_f32_f16<<<4608, 256, 0, stream>>>(wo, wo16, WSZ / 8);
  cast_f32_f16<<<4608, 256, 0, stream>>>(wao, wao16, WSZ / 8);
  gemm256_out<<<132, 512, 0, stream>>>(ob, wo16, bo, wao16, bao, out);
}